// Round 5
// baseline (2752.129 us; speedup 1.0000x reference)
//
#include <hip/hip_runtime.h>
#include <math.h>

// B=256, T=2048, D=64, U=128, 4U=512, COND=32
namespace {
constexpr int kB    = 256;
constexpr int kT    = 2048;
constexpr int kD    = 64;
constexpr int kU    = 128;
constexpr int kCOND = 32;
}

typedef _Float16 h2 __attribute__((ext_vector_type(2)));

__device__ __forceinline__ float sig_(float z) {
    return 1.0f / (1.0f + __expf(-z));
}
__device__ __forceinline__ float tanh_(float z) {
    float ez = __expf(-2.0f * fabsf(z));
    float t  = (1.0f - ez) / (1.0f + ez);
    return copysignf(t, z);
}
__device__ __forceinline__ float dot2_(h2 a, h2 b, float c) {
    return __builtin_amdgcn_fdot2(a, b, c, false);   // v_dot2_f32_f16
}
// DPP permute (pure VALU). 0xB1=quad_perm xor1, 0x4E=quad_perm xor2,
// 0x128=row_ror:8 == xor8 within a 16-lane row. (All verified by rounds 3/4.)
template <int CTRL>
__device__ __forceinline__ float dppmov_(float v) {
    return __int_as_float(
        __builtin_amdgcn_update_dpp(0, __float_as_int(v), CTRL, 0xF, 0xF, true));
}

union F4H { float4 f4; h2 h[4]; };

// One WG (1024 thr = 16 waves) per batch element, persistent over T steps.
// Thread = (colgroup j in [0,128), slice s in [0,8)); columns {j+128i}.
// SINGLE barrier per step:
//  - h and x live in DOUBLE-BUFFERED f16 LDS; step t reads buf[t&1],
//    writes buf[(t+1)&1] -> no read/write race with one barrier.
//  - after the DPP reduce-scatter, 2 more DPP exchange rounds give every
//    lane all 4 gate preacts of its column j; gates + c/h update are
//    computed replicated (8x) in ALL lanes -> no g4 LDS round-trip, no
//    serial 2-wave gate phase.
__global__ __launch_bounds__(1024, 4)
__attribute__((amdgpu_waves_per_eu(4, 4)))
void lstm_1bar(const float* __restrict__ x,     // [B,T,D]
               const float* __restrict__ cond,  // [B,COND]
               const float* __restrict__ Wc,    // [COND,U]
               const float* __restrict__ bc,    // [U]
               const float* __restrict__ Wk,    // [D,4U]
               const float* __restrict__ Uk,    // [U,4U]
               const float* __restrict__ bias,  // [4U]
               float* __restrict__ out) {       // [B,U]
    const int b    = blockIdx.x;
    const int tid  = threadIdx.x;
    const int lane = tid & 63;
    const int wav  = tid >> 6;
    const int s    = (lane & 3) | ((lane >> 1) & 4);        // lane bits 0,1,3
    const int jl   = ((lane >> 2) & 1) | ((lane >> 3) & 6); // lane bits 2,4,5
    const int j    = wav * 8 + jl;                          // colgroup 0..127
    const bool s0 = (lane & 1) != 0;
    const bool s1 = (lane & 2) != 0;
    const bool s2 = (lane & 8) != 0;

    __shared__ __align__(16) _Float16 hbuf[2][kU];   // h state, double-buffered
    __shared__ __align__(16) _Float16 xbuf[2][kD];   // x_t, double-buffered

    // ---- f16 weights: 4 cols x (4 x-pairs + 8 h-pairs) = 48 h2 VGPRs ----
    h2 wx[4][4];
    h2 wh[4][8];
#pragma unroll
    for (int i = 0; i < 4; ++i) {
        const int c = j + kU * i;
#pragma unroll
        for (int kk = 0; kk < 4; ++kk) {
            const int d = s * 8 + 2 * kk;
            h2 w; w.x = (_Float16)Wk[d * 512 + c]; w.y = (_Float16)Wk[(d + 1) * 512 + c];
            wx[i][kk] = w;
        }
#pragma unroll
        for (int kk = 0; kk < 8; ++kk) {
            const int u = s * 16 + 2 * kk;
            h2 w; w.x = (_Float16)Uk[u * 512 + c]; w.y = (_Float16)Uk[(u + 1) * 512 + c];
            wh[i][kk] = w;
        }
    }

    // ---- per-column biases (applied once, post-reduction) ----
    const float bi  = bias[j];
    const float bf  = bias[kU + j];
    const float bcg = bias[2 * kU + j];
    const float bo  = bias[3 * kU + j];

    // ---- initial state for column j (replicated across the 8 s-lanes) ----
    float c_reg;
    {
        float a = bc[j];
        const float* cr = cond + b * kCOND;
#pragma unroll
        for (int k = 0; k < kCOND; ++k) a = fmaf(cr[k], Wc[k * kU + j], a);
        c_reg = a;
        if (!s0 && !s1 && !s2) hbuf[0][j] = (_Float16)a;
    }
    const float* xb = x + (size_t)b * kT * kD;
    if (tid < kD) xbuf[0][tid] = (_Float16)xb[tid];
    float h_out = 0.0f;
    __syncthreads();

#pragma unroll 1
    for (int t = 0; t < kT; ++t) {
        const int cur = t & 1;
        const int nxt = cur ^ 1;

        // stage x[t+1] (64 threads, issued first: full step to cover latency)
        float xv = 0.0f;
        if (tid < kD) {
            int tn = t + 1; if (tn == kT) tn = kT - 1;
            xv = xb[(size_t)tn * kD + tid];
        }

        // ---- dots over this thread's K-slice (x from LDS, h from LDS) ----
        F4H ux, uh0, uh1;
        ux.f4  = *(const float4*)(&xbuf[cur][8 * s]);
        uh0.f4 = *(const float4*)(&hbuf[cur][16 * s]);
        uh1.f4 = *(const float4*)(&hbuf[cur][16 * s + 8]);

        float a0 = 0.0f, a1 = 0.0f, a2 = 0.0f, a3 = 0.0f;
#pragma unroll
        for (int kk = 0; kk < 4; ++kk) {
            a0 = dot2_(ux.h[kk], wx[0][kk], a0);
            a1 = dot2_(ux.h[kk], wx[1][kk], a1);
            a2 = dot2_(ux.h[kk], wx[2][kk], a2);
            a3 = dot2_(ux.h[kk], wx[3][kk], a3);
        }
#pragma unroll
        for (int kk = 0; kk < 4; ++kk) {
            a0 = dot2_(uh0.h[kk], wh[0][kk], a0);
            a1 = dot2_(uh0.h[kk], wh[1][kk], a1);
            a2 = dot2_(uh0.h[kk], wh[2][kk], a2);
            a3 = dot2_(uh0.h[kk], wh[3][kk], a3);
        }
#pragma unroll
        for (int kk = 0; kk < 4; ++kk) {
            a0 = dot2_(uh1.h[kk], wh[0][4 + kk], a0);
            a1 = dot2_(uh1.h[kk], wh[1][4 + kk], a1);
            a2 = dot2_(uh1.h[kk], wh[2][4 + kk], a2);
            a3 = dot2_(uh1.h[kk], wh[3][4 + kk], a3);
        }

        // ---- reduce-scatter over the 8 s-lanes (bits 3,1,0) ----
        float sAx = s2 ? a0 : a2;
        float sAy = s2 ? a1 : a3;
        float rAx = dppmov_<0x128>(sAx);
        float rAy = dppmov_<0x128>(sAy);
        float vA  = (s2 ? a2 : a0) + rAx;
        float vB  = (s2 ? a3 : a1) + rAy;
        float sB  = s1 ? vA : vB;
        float rB  = dppmov_<0x4E>(sB);
        float vC  = (s1 ? vB : vA) + rB;
        float g   = vC + dppmov_<0xB1>(vC);   // lane holds gate i=2*s2+s1 of col j

        // ---- exchange: give every lane all 4 gates of its column j ----
        float r1  = dppmov_<0x4E>(g);         // partner s1^1
        float gLo = s1 ? r1 : g;              // gate 2*s2
        float gHi = s1 ? g : r1;              // gate 2*s2+1
        float rLo = dppmov_<0x128>(gLo);      // partner s2^1
        float rHi = dppmov_<0x128>(gHi);
        float g0  = s2 ? rLo : gLo;           // i
        float g1  = s2 ? rHi : gHi;           // f
        float g2  = s2 ? gLo : rLo;           // c~
        float g3  = s2 ? gHi : rHi;           // o

        // ---- gates + state update, replicated in all 8 s-lanes ----
        float iv = sig_(g0 + bi);
        float fv = sig_(g1 + bf);
        float cb = tanh_(g2 + bcg);
        float ov = sig_(g3 + bo);
        c_reg = fmaf(fv, c_reg, iv * cb);
        h_out = ov * tanh_(c_reg);

        if (!s0 && !s1 && !s2) hbuf[nxt][j] = (_Float16)h_out;  // s==0 lane
        if (tid < kD)          xbuf[nxt][tid] = (_Float16)xv;

        __syncthreads();
    }

    if (!s0 && !s1 && !s2) out[b * kU + j] = h_out;
}

extern "C" void kernel_launch(void* const* d_in, const int* in_sizes, int n_in,
                              void* d_out, int out_size, void* d_ws, size_t ws_size,
                              hipStream_t stream) {
    const float* x    = (const float*)d_in[0];
    const float* cond = (const float*)d_in[1];
    const float* Wc   = (const float*)d_in[2];
    const float* bc   = (const float*)d_in[3];
    const float* Wk   = (const float*)d_in[4];
    const float* Uk   = (const float*)d_in[5];
    const float* b    = (const float*)d_in[6];
    float* out = (float*)d_out;

    lstm_1bar<<<dim3(kB), dim3(1024), 0, stream>>>(x, cond, Wc, bc, Wk, Uk, b, out);
}

// Round 6
// 2184.861 us; speedup vs baseline: 1.2596x; 1.2596x over previous
//
#include <hip/hip_runtime.h>
#include <math.h>

// B=256, T=2048, D=64, U=128, 4U=512, COND=32
namespace {
constexpr int kB    = 256;
constexpr int kT    = 2048;
constexpr int kD    = 64;
constexpr int kU    = 128;
constexpr int kCOND = 32;
}

typedef _Float16 h2 __attribute__((ext_vector_type(2)));

__device__ __forceinline__ float sig_(float z) {
    return 1.0f / (1.0f + __expf(-z));
}
__device__ __forceinline__ float tanh_(float z) {
    float ez = __expf(-2.0f * fabsf(z));
    float t  = (1.0f - ez) / (1.0f + ez);
    return copysignf(t, z);
}
__device__ __forceinline__ float dot2_(h2 a, h2 b, float c) {
    return __builtin_amdgcn_fdot2(a, b, c, false);   // v_dot2_f32_f16
}
// xor1 butterfly add via DPP quad_perm [1,0,3,2] (verified rounds 3-5)
__device__ __forceinline__ float dppadd1_(float v) {
    int p = __builtin_amdgcn_update_dpp(0, __float_as_int(v), 0xB1, 0xF, 0xF, true);
    return v + __int_as_float(p);
}
// Pin a packed value: asm-defined => NOT rematerializable by the allocator.
// (Rounds 2/5 failure mode: allocator remats the weight load+cvt chain into
// the t-loop when pressure exceeds its occupancy-heuristic budget.)
__device__ __forceinline__ void pin_(h2& w) {
    float f = __builtin_bit_cast(float, w);
    asm volatile("" : "+v"(f));
    w = __builtin_bit_cast(h2, f);
}
__device__ __forceinline__ void pinf_(float& f) {
    asm volatile("" : "+v"(f));
}

union F4H { float4 f4; h2 h[4]; };

// 512 threads (8 waves) per batch element, persistent over T steps.
// Thread = (column-pair cg in [0,256), K-slice s in {0,1}); owns columns
// {cg, cg+256} over K-slice [32s..32s+32)_x ++ [64s..64s+64)_h:
// 96 h2 weight VGPRs. 512-thread regime => compiler budget 128 VGPRs
// (measured round 1), need ~125. Split-K reduce = ONE dpp-xor1 add.
// x[t+1] staged to LDS by wave 2 a full step ahead; x-part dots for t+1
// run between the two barriers, hidden under the 2-wave gate phase.
__global__ __launch_bounds__(512, 2)
__attribute__((amdgpu_waves_per_eu(2, 2)))
void lstm_512(const float* __restrict__ x,     // [B,T,D]
              const float* __restrict__ cond,  // [B,COND]
              const float* __restrict__ Wc,    // [COND,U]
              const float* __restrict__ bc,    // [U]
              const float* __restrict__ Wk,    // [D,4U]
              const float* __restrict__ Uk,    // [U,4U]
              const float* __restrict__ bias,  // [4U]
              float* __restrict__ out) {       // [B,U]
    const int b    = blockIdx.x;
    const int tid  = threadIdx.x;
    const int lane = tid & 63;
    const int wav  = tid >> 6;
    const int s    = lane & 1;                 // K-slice (lane bit 0)
    const int cg   = (wav << 5) | (lane >> 1); // column pair id [0,256)
    const int c0   = cg;                       // gate i (cg<128) / f
    const int c1   = cg + 256;                 // gate c~ / o
    const int pub  = cg + (s << 8);            // publish word (2-way bank, free)

    __shared__ __align__(16) _Float16 hbuf[2][kU];  // h, f16, double-buffered
    __shared__ __align__(16) _Float16 xbuf[2][kD];  // x_t, f16, double-buffered
    __shared__ float g4[512];                       // gate preacts, g4[column]

    // ---- pack f16 weights: per column 16 x-pairs + 32 h-pairs ----
    h2 wx0[16], wx1[16], wh0[32], wh1[32];
#pragma unroll
    for (int k = 0; k < 16; ++k) {
        const int d = 32 * s + 2 * k;
        h2 w;
        w.x = (_Float16)Wk[d * 512 + c0]; w.y = (_Float16)Wk[(d + 1) * 512 + c0];
        wx0[k] = w;
        w.x = (_Float16)Wk[d * 512 + c1]; w.y = (_Float16)Wk[(d + 1) * 512 + c1];
        wx1[k] = w;
    }
#pragma unroll
    for (int k = 0; k < 32; ++k) {
        const int u = 64 * s + 2 * k;
        h2 w;
        w.x = (_Float16)Uk[u * 512 + c0]; w.y = (_Float16)Uk[(u + 1) * 512 + c0];
        wh0[k] = w;
        w.x = (_Float16)Uk[u * 512 + c1]; w.y = (_Float16)Uk[(u + 1) * 512 + c1];
        wh1[k] = w;
    }
#pragma unroll
    for (int k = 0; k < 16; ++k) { pin_(wx0[k]); pin_(wx1[k]); }
#pragma unroll
    for (int k = 0; k < 32; ++k) { pin_(wh0[k]); pin_(wh1[k]); }

    // biases folded into the s==0 lane's accumulator init
    float b0 = s ? 0.0f : bias[c0];
    float b1 = s ? 0.0f : bias[c1];
    pinf_(b0); pinf_(b1);

    // ---- initial state: h0 = c0 = cond @ Wc + bc (threads 0..127) ----
    float c_reg = 0.0f, h_out = 0.0f;
    if (tid < kU) {
        float a = bc[tid];
        const float* cr = cond + b * kCOND;
#pragma unroll
        for (int k = 0; k < kCOND; ++k) a = fmaf(cr[k], Wc[k * kU + tid], a);
        c_reg = a;
        hbuf[0][tid] = (_Float16)a;
    }
    const float* xb = x + (size_t)b * kT * kD;
    if (wav == 2) xbuf[0][lane] = (_Float16)xb[lane];
    __syncthreads();

    // x-part dots (+bias) for the given buffer -> (p0, p1)
    auto xdots = [&](int buf, float& p0, float& p1) {
        const F4H* xp = (const F4H*)&xbuf[buf][32 * s];
        p0 = b0; p1 = b1;
#pragma unroll
        for (int q = 0; q < 4; ++q) {
            F4H u = xp[q];
#pragma unroll
            for (int k = 0; k < 4; ++k) {
                p0 = dot2_(u.h[k], wx0[4 * q + k], p0);
                p1 = dot2_(u.h[k], wx1[4 * q + k], p1);
            }
        }
    };

    float px0, px1;
    xdots(0, px0, px1);   // x-part for t=0

#pragma unroll 1
    for (int t = 0; t < kT; ++t) {
        const int cur = t & 1;
        const int nxt = cur ^ 1;

        // wave 2: issue x[t+1] load early (coalesced 256 B)
        float xv = 0.0f;
        if (wav == 2) {
            int tn = t + 1; if (tn == kT) tn = kT - 1;
            xv = xb[(size_t)tn * kD + lane];
        }

        // ---- h-part dots over this thread's slice (broadcast b128 reads) ----
        float a0 = px0, a1 = px1;
        const F4H* hp = (const F4H*)&hbuf[cur][64 * s];
#pragma unroll
        for (int q = 0; q < 8; ++q) {
            F4H u = hp[q];
#pragma unroll
            for (int k = 0; k < 4; ++k) {
                a0 = dot2_(u.h[k], wh0[4 * q + k], a0);
                a1 = dot2_(u.h[k], wh1[4 * q + k], a1);
            }
        }

        // split-K reduce (one butterfly) + publish (one b32, 2-way banks)
        a0 = dppadd1_(a0);
        a1 = dppadd1_(a1);
        g4[pub] = s ? a1 : a0;

        if (wav == 2) xbuf[nxt][lane] = (_Float16)xv;
        __syncthreads();

        // ---- window: x-dots for t+1 (all waves) hide the gate phase ----
        xdots(nxt, px0, px1);

        // gate phase: threads 0..127 own state element u=tid
        if (tid < kU) {
            float g0 = g4[tid];            // i
            float g1 = g4[tid + 128];      // f
            float g2 = g4[tid + 256];      // c~
            float g3 = g4[tid + 384];      // o
            float iv = sig_(g0);
            float fv = sig_(g1);
            float cb = tanh_(g2);
            float ov = sig_(g3);
            c_reg = fmaf(fv, c_reg, iv * cb);
            h_out = ov * tanh_(c_reg);
            hbuf[nxt][tid] = (_Float16)h_out;
        }
        __syncthreads();
    }

    if (tid < kU) out[b * kU + tid] = h_out;
}

extern "C" void kernel_launch(void* const* d_in, const int* in_sizes, int n_in,
                              void* d_out, int out_size, void* d_ws, size_t ws_size,
                              hipStream_t stream) {
    const float* x    = (const float*)d_in[0];
    const float* cond = (const float*)d_in[1];
    const float* Wc   = (const float*)d_in[2];
    const float* bc   = (const float*)d_in[3];
    const float* Wk   = (const float*)d_in[4];
    const float* Uk   = (const float*)d_in[5];
    const float* b    = (const float*)d_in[6];
    float* out = (float*)d_out;

    lstm_512<<<dim3(kB), dim3(512), 0, stream>>>(x, cond, Wc, bc, Wk, Uk, b, out);
}

// Round 7
// 1792.501 us; speedup vs baseline: 1.5354x; 1.2189x over previous
//
#include <hip/hip_runtime.h>
#include <math.h>

// B=256, T=2048, D=64, U=128, 4U=512, COND=32
namespace {
constexpr int kB    = 256;
constexpr int kT    = 2048;
constexpr int kD    = 64;
constexpr int kU    = 128;
constexpr int kCOND = 32;
}

typedef _Float16 f16x8 __attribute__((ext_vector_type(8)));
typedef float    f32x4 __attribute__((ext_vector_type(4)));

__device__ __forceinline__ float sig_(float z) {
    return 1.0f / (1.0f + __expf(-z));
}
__device__ __forceinline__ float tanh_(float z) {
    float ez = __expf(-2.0f * fabsf(z));
    float t  = (1.0f - ez) / (1.0f + ez);
    return copysignf(t, z);
}
// pin a 16B fragment so the allocator cannot rematerialize its global loads
__device__ __forceinline__ void pin4_(f16x8& w) {
    f32x4 t = __builtin_bit_cast(f32x4, w);
    asm volatile("" : "+v"(t));
    w = __builtin_bit_cast(f16x8, t);
}

// One WG (512 thr = 8 waves) per batch element, persistent over T steps.
// MFMA m-broadcast trick: A-operand = activations a[192] replicated over all
// 16 M-rows (per-lane A-frag read is a broadcast of the same 16B -> D is
// row-constant and EVERY lane holds G[16*tile + (lane&15)] in all 4 acc regs).
// B-operand = weights, fragment rule per m91 (n=lane&15, k=quad*8+j), loaded
// once into registers (24 frags = 96 VGPRs/wave).
// Wave w owns N-tiles {w, w+8, w+16, w+24} = the i,f,c~,o columns of states
// u = 16w + (lane&15): all four gate preacts land in-lane, zero LDS shuffle.
// Single barrier/step, double-buffered a=[x(64);h(128)] f16 in LDS.
__global__ __launch_bounds__(512, 2)
void lstm_mfma(const float* __restrict__ x,     // [B,T,D]
               const float* __restrict__ cond,  // [B,COND]
               const float* __restrict__ Wc,    // [COND,U]
               const float* __restrict__ bc,    // [U]
               const float* __restrict__ Wk,    // [D,4U]
               const float* __restrict__ Uk,    // [U,4U]
               const float* __restrict__ bias,  // [4U]
               float* __restrict__ out) {       // [B,U]
    const int b    = blockIdx.x;
    const int tid  = threadIdx.x;
    const int lane = tid & 63;
    const int w    = tid >> 6;     // wave 0..7
    const int q    = lane >> 4;    // quad 0..3
    const int c    = lane & 15;
    const int u    = 16 * w + c;   // this lane's state element

    __shared__ __align__(16) _Float16 abuf[2][192];  // [x(64); h(128)], dbuf

    // ---- B-frags: 4 tiles x 6 K-chunks, k = 32*kc + 8*q + j, col = 16t + c ----
    f16x8 wfrag[4][6];
    float btile[4];
#pragma unroll
    for (int jt = 0; jt < 4; ++jt) {
        const int t   = w + 8 * jt;          // tile; jt = gate index (i,f,c~,o)
        const int col = 16 * t + c;
#pragma unroll
        for (int kc = 0; kc < 6; ++kc) {
            f16x8 f;
#pragma unroll
            for (int j = 0; j < 8; ++j) {
                const int k = 32 * kc + 8 * q + j;
                const float v = (k < kD) ? Wk[k * 512 + col]
                                         : Uk[(k - kD) * 512 + col];
                f[j] = (_Float16)v;
            }
            wfrag[jt][kc] = f;
        }
        btile[jt] = bias[col];
    }
#pragma unroll
    for (int jt = 0; jt < 4; ++jt)
#pragma unroll
        for (int kc = 0; kc < 6; ++kc) pin4_(wfrag[jt][kc]);

    // ---- initial state: c0 = h0 = bc[u] + cond[b,:] @ Wc[:,u] ----
    float c_reg;
    {
        float a = bc[u];
        const float* cr = cond + b * kCOND;
#pragma unroll
        for (int kk = 0; kk < kCOND; ++kk) a = fmaf(cr[kk], Wc[kk * kU + u], a);
        c_reg = a;
        if (q == 0) abuf[0][kD + u] = (_Float16)a;
    }
    const float* xb = x + (size_t)b * kT * kD;
    if (tid < kD) abuf[0][tid] = (_Float16)xb[tid];   // x_0
    float h_out = 0.0f;
    __syncthreads();

#pragma unroll 1
    for (int t = 0; t < kT; ++t) {
        const int cur = t & 1;
        const int nxt = cur ^ 1;

        // prefetch x[t+1] (wave 0): global -> reg, staged to LDS at step end
        float xv = 0.0f;
        if (tid < kD) {
            int tn = t + 1; if (tn == kT) tn = kT - 1;
            xv = xb[(size_t)tn * kD + tid];
        }

        // A-frags: broadcast reads (all 16 c-lanes read the same 16B)
        f16x8 af[6];
#pragma unroll
        for (int kc = 0; kc < 6; ++kc)
            af[kc] = *(const f16x8*)&abuf[cur][32 * kc + 8 * q];

        // accumulators init to bias (row-constant C)
        f32x4 acc[4];
#pragma unroll
        for (int jt = 0; jt < 4; ++jt)
            acc[jt] = (f32x4){btile[jt], btile[jt], btile[jt], btile[jt]};

#pragma unroll
        for (int kc = 0; kc < 6; ++kc) {
#pragma unroll
            for (int jt = 0; jt < 4; ++jt)
                acc[jt] = __builtin_amdgcn_mfma_f32_16x16x32_f16(
                    af[kc], wfrag[jt][kc], acc[jt], 0, 0, 0);
        }

        // gates: D is row-constant -> reg 0 of each tile = G[16t + c]
        const float iv = sig_(acc[0][0]);
        const float fv = sig_(acc[1][0]);
        const float cb = tanh_(acc[2][0]);
        const float ov = sig_(acc[3][0]);
        c_reg = fmaf(fv, c_reg, iv * cb);
        h_out = ov * tanh_(c_reg);

        if (q == 0)   abuf[nxt][kD + u] = (_Float16)h_out;  // h_{t+1}
        if (tid < kD) abuf[nxt][tid]    = (_Float16)xv;     // x_{t+1}
        __syncthreads();
    }

    if (q == 0) out[b * kU + u] = h_out;
}

extern "C" void kernel_launch(void* const* d_in, const int* in_sizes, int n_in,
                              void* d_out, int out_size, void* d_ws, size_t ws_size,
                              hipStream_t stream) {
    const float* x    = (const float*)d_in[0];
    const float* cond = (const float*)d_in[1];
    const float* Wc   = (const float*)d_in[2];
    const float* bc   = (const float*)d_in[3];
    const float* Wk   = (const float*)d_in[4];
    const float* Uk   = (const float*)d_in[5];
    const float* b    = (const float*)d_in[6];
    float* out = (float*)d_out;

    lstm_mfma<<<dim3(kB), dim3(512), 0, stream>>>(x, cond, Wc, bc, Wk, Uk, b, out);
}